// Round 6
// baseline (467.205 us; speedup 1.0000x reference)
//
#include <hip/hip_runtime.h>
#include <hip/hip_bf16.h>

// GRUCell fused cell. B=16384, d=1024, 2d=2048.
//   inp  = LN(concat(x,h); g1,b1) * dm
//   gates= inp @ Wg + bg ; r=sig(gates[:, :d]); z=sig(gates[:, d:])
//   inp2 = LN(concat(x, h*r); g2,b2) * dm
//   u    = tanh(inp2 @ Wu + bu)
//   out  = h*z + (1-z)*u
//
// R6: faithful 8-phase (m201-style) GEMM. BK=64, double-buffered (2x64KB),
// each K-tile split into k-halves (k0=0..31, k1=32..63). 4 phases per K-tile:
//   P(cs=0): read A(kh) 8x b128 + B(kh,left) 2x b128 ; stage 1 half ; bar;
//            lgkm0; setprio1; 16 MFMA; setprio0; bar
//   P(cs=1): read B(kh,right) 2x b128 (A reused in regs); same structure.
// Stage schedule (iter i computes tiles 2i (d0, P1-4) and 2i+1 (d1, P5-8)):
//   P1:(2i+1).A-k1->d1  P2:(2i+1).B-k1->d1  P3:(2i+2).A-k0->d0
//   P4:(2i+2).B-k0->d0  P5:(2i+2).A-k1->d0  P6:(2i+2).B-k1->d0
//   P7:(2i+3).A-k0->d1  P8:(2i+3).B-k0->d1
// Checkpoints: vmcnt(4) after P4's MFMA and after P8's MFMA (2 half-stages
// = 4 loads allowed outstanding). Liveness proof:
//   reads  P1(d0.k0): staged prev P3,P4; confirmed prev-P8 vmcnt(4) (allows
//          prev P5-P8 =8 outst -> confirms thru prev P6). OK
//   reads  P3(d0.k1): staged prev P5,P6; confirmed prev-P8 vmcnt(4). OK
//   reads  P5(d1.k0): staged prev P7,P8; confirmed this-P4 vmcnt(4) (allows
//          P3,P4 -> confirms thru P2, incl prev P7,P8). OK
//   reads  P7(d1.k1): staged this P1,P2; confirmed this-P4 vmcnt(4). OK
//   writes: each stage targets a region whose last reader phase closed with
//          a barrier >=1 phase earlier (d1.k1 dead after prev P8; d0.k0 dead
//          after P2; d0.k1 dead after P4; d1.k0 dead after P6). OK
// Last iter: P3..P8 stages skipped -> P4 checkpoint must be vmcnt(0) (its
// vmcnt(4) would pass without confirming P1,P2's stages needed by P7).
//
// ws layout (bytes):
//   [0,            8388608)  WgT  bf16 [2048][2048]  (WgT[n][k] = Wg[k][n])
//   [8388608,     12582912)  WuT  bf16 [1024][2048]
//   [12582912,    79691776)  ln   bf16 [16384][2048] (LN1 then LN2 output)
//   [79691776,   113246208)  hr   bf16 [16384][1024] (h * r)
// z (f32) staged in d_out between GEMM1 and GEMM2 (each element read only by
// the thread that overwrites it in GEMM2's epilogue).

#define BATCH 16384
#define DDIM  1024
#define TWOD  2048
#define LNEPS 1e-5f

#define GBM 256
#define GBN 256
#define GBK 64
#define NTH 512

typedef __bf16 bf16x8 __attribute__((ext_vector_type(8)));
typedef float  f32x4  __attribute__((ext_vector_type(4)));
typedef unsigned short ushort4v __attribute__((ext_vector_type(4)));

__device__ __forceinline__ unsigned short f2bf(float f) {
    unsigned int u = __builtin_bit_cast(unsigned int, f);
    u = (u + 0x7FFFu + ((u >> 16) & 1u)) >> 16;   // round-to-nearest-even
    return (unsigned short)u;
}
__device__ __forceinline__ float bf2f(unsigned short s) {
    unsigned int u = ((unsigned int)s) << 16;
    return __builtin_bit_cast(float, u);
}
__device__ __forceinline__ void gload16(const void* g, void* l) {
    __builtin_amdgcn_global_load_lds((__attribute__((address_space(1))) void*)(g),
                                     (__attribute__((address_space(3))) void*)(l),
                                     16u, 0, 0);
}

// ---------------- weight transpose + f32->bf16 cast ------------------------
__global__ __launch_bounds__(256) void wtrans(const float* __restrict__ W,
                                              unsigned short* __restrict__ WT,
                                              int K, int N) {
    __shared__ float tile[32][33];
    const int k0 = blockIdx.x * 32;
    const int n0 = blockIdx.y * 32;
    const int tx = threadIdx.x & 31;
    const int ty = threadIdx.x >> 5;
#pragma unroll
    for (int p = 0; p < 32; p += 8)
        tile[p + ty][tx] = W[(size_t)(k0 + p + ty) * N + n0 + tx];
    __syncthreads();
#pragma unroll
    for (int p = 0; p < 32; p += 8)
        WT[(size_t)(n0 + p + ty) * K + k0 + tx] = f2bf(tile[tx][p + ty]);
}

// ---------------- fused LayerNorm over concat(x, second) -------------------
template <bool SECOND_BF16>
__global__ __launch_bounds__(256) void ln_kernel(const float* __restrict__ x,
                                                 const void* __restrict__ h2,
                                                 const float* __restrict__ g,
                                                 const float* __restrict__ bt,
                                                 const float* __restrict__ dm,
                                                 unsigned short* __restrict__ out) {
    const int row  = blockIdx.x;
    const int tid  = threadIdx.x;
    const int lane = tid & 63;
    const int w    = tid >> 6;

    const float4 xl = reinterpret_cast<const float4*>(x + (size_t)row * DDIM)[tid];
    float hv[4];
    if (SECOND_BF16) {
        const ushort4v hl = reinterpret_cast<const ushort4v*>(
            (const unsigned short*)h2 + (size_t)row * DDIM)[tid];
#pragma unroll
        for (int j = 0; j < 4; ++j) hv[j] = bf2f(hl[j]);
    } else {
        const float4 hl = reinterpret_cast<const float4*>(
            (const float*)h2 + (size_t)row * DDIM)[tid];
        hv[0] = hl.x; hv[1] = hl.y; hv[2] = hl.z; hv[3] = hl.w;
    }
    float xv[4] = {xl.x, xl.y, xl.z, xl.w};

    float s = 0.f, ss = 0.f;
#pragma unroll
    for (int j = 0; j < 4; ++j) { s += xv[j] + hv[j]; ss += xv[j]*xv[j] + hv[j]*hv[j]; }
#pragma unroll
    for (int o = 32; o; o >>= 1) { s += __shfl_xor(s, o); ss += __shfl_xor(ss, o); }
    __shared__ float red[8];
    if (lane == 0) { red[w] = s; red[4 + w] = ss; }
    __syncthreads();
    s  = red[0] + red[1] + red[2] + red[3];
    ss = red[4] + red[5] + red[6] + red[7];
    const float inv  = 1.0f / (float)TWOD;
    const float mu   = s * inv;
    const float var  = ss * inv - mu * mu;
    const float rstd = rsqrtf(var + LNEPS);

    {
        const float4 gv = reinterpret_cast<const float4*>(g)[tid];
        const float4 bv = reinterpret_cast<const float4*>(bt)[tid];
        const float4 dv = reinterpret_cast<const float4*>(dm)[tid];
        ushort4v pk;
        pk[0] = f2bf(((xv[0] - mu) * rstd * gv.x + bv.x) * dv.x);
        pk[1] = f2bf(((xv[1] - mu) * rstd * gv.y + bv.y) * dv.y);
        pk[2] = f2bf(((xv[2] - mu) * rstd * gv.z + bv.z) * dv.z);
        pk[3] = f2bf(((xv[3] - mu) * rstd * gv.w + bv.w) * dv.w);
        reinterpret_cast<ushort4v*>(out + (size_t)row * TWOD)[tid] = pk;
    }
    {
        const float4 gv = reinterpret_cast<const float4*>(g)[256 + tid];
        const float4 bv = reinterpret_cast<const float4*>(bt)[256 + tid];
        const float4 dv = reinterpret_cast<const float4*>(dm)[256 + tid];
        ushort4v pk;
        pk[0] = f2bf(((hv[0] - mu) * rstd * gv.x + bv.x) * dv.x);
        pk[1] = f2bf(((hv[1] - mu) * rstd * gv.y + bv.y) * dv.y);
        pk[2] = f2bf(((hv[2] - mu) * rstd * gv.z + bv.z) * dv.z);
        pk[3] = f2bf(((hv[3] - mu) * rstd * gv.w + bv.w) * dv.w);
        reinterpret_cast<ushort4v*>(out + (size_t)row * TWOD + DDIM)[tid] = pk;
    }
}

// ---------------- 256x256 8-wave 8-phase bf16 GEMM -------------------------
// LDS map (per dbuf d in {0,1}, 64KB): A-k0 @0, B-k0 @16K, A-k1 @32K, B-k1 @48K.
// Region = 256 rows x 32 k bf16 (row = 64B = 4x16B granules).
// Granule-XOR swizzle: phys granule = logical ^ ((row>>1)&3) (0 conflicts,
// PMC-verified R2). global_load_lds dest linear, SOURCE pre-swizzled.
template <int EPI>
__global__ __launch_bounds__(NTH, 2) void gemm8p(const unsigned short* __restrict__ A,
                                                 const unsigned short* __restrict__ BT,
                                                 const float* __restrict__ bias,
                                                 const float* __restrict__ h,
                                                 unsigned short* __restrict__ hr,
                                                 float* __restrict__ zbuf,
                                                 float* __restrict__ outp) {
    extern __shared__ char sm[];      // 131072 bytes
    const int tid  = threadIdx.x;
    const int lane = tid & 63;
    const int w    = tid >> 6;        // 0..7
    const int wm   = w >> 2;          // 0..1 (M-warp)
    const int wn   = w & 3;           // 0..3 (N-warp)
    const int q    = lane >> 4;       // 0..3 (K-chunk)
    const int r16  = lane & 15;
    const size_t m0 = (size_t)blockIdx.x * GBM;
    const int    n0 = blockIdx.y * GBN;

    const unsigned short* Ag = A  + m0 * TWOD;
    const unsigned short* Bg = BT + (size_t)n0 * TWOD;

    // staging sources: thread t covers granules t and t+512 of a 16KB half
    // (1024 granules = 256 rows x 4). row(g)=g>>2; src col-granule pre-swizzled.
    const int rg0 = tid >> 2;                       // 0..127
    const int sg  = (tid & 3) ^ ((rg0 >> 1) & 3);   // same for rg0+128
    const unsigned short* aS0 = Ag + (size_t)rg0 * TWOD + sg * 8;
    const unsigned short* aS1 = Ag + (size_t)(rg0 + 128) * TWOD + sg * 8;
    const unsigned short* bS0 = Bg + (size_t)rg0 * TWOD + sg * 8;
    const unsigned short* bS1 = Bg + (size_t)(rg0 + 128) * TWOD + sg * 8;
    const unsigned woff = (unsigned)w * 1024u;      // gload dest: +lane*16 by HW

#define RG(d, kh, isB) ((unsigned)(d)*65536u + (unsigned)(kh)*32768u + (unsigned)(isB)*16384u)
#define STG(isB, T, kh, d) { \
    const unsigned b_ = RG(d, kh, isB) + woff; \
    const int ko_ = (T) * GBK + (kh) * 32; \
    gload16(((isB) ? bS0 : aS0) + ko_, sm + b_); \
    gload16(((isB) ? bS1 : aS1) + ko_, sm + b_ + 8192u); }

    // frag-read offsets (phys granule = q ^ ((r16>>1)&3); row-parity trick)
    const unsigned pgo     = (unsigned)((q ^ ((r16 >> 1) & 3)) * 16);
    const unsigned arowoff = (unsigned)((wm * 128 + r16) * 64) + pgo;  // + i*1024
    const unsigned browoff = (unsigned)((wn * 64 + r16) * 64) + pgo;   // + cs*2048 + n*1024

#define BARR  asm volatile("s_barrier" ::: "memory")
#define LGKM0 asm volatile("s_waitcnt lgkmcnt(0)" ::: "memory")
#define VMC4  asm volatile("s_waitcnt vmcnt(4)" ::: "memory")
#define VMC0  asm volatile("s_waitcnt vmcnt(0)" ::: "memory")
#define RDA8(d, kh) { _Pragma("unroll") for (int i = 0; i < 8; ++i) \
    af[i] = *(const bf16x8*)(sm + RG(d, kh, 0) + arowoff + (unsigned)i * 1024u); }
#define RDB2(d, kh, cs) { _Pragma("unroll") for (int n = 0; n < 2; ++n) \
    bf[n] = *(const bf16x8*)(sm + RG(d, kh, 1) + browoff + (unsigned)(cs) * 2048u + (unsigned)n * 1024u); }
#define MFMA16(cs) { __builtin_amdgcn_s_setprio(1); \
    _Pragma("unroll") for (int i = 0; i < 8; ++i) { \
      acc[i][(cs)*2+0] = __builtin_amdgcn_mfma_f32_16x16x32_bf16(af[i], bf[0], acc[i][(cs)*2+0], 0, 0, 0); \
      acc[i][(cs)*2+1] = __builtin_amdgcn_mfma_f32_16x16x32_bf16(af[i], bf[1], acc[i][(cs)*2+1], 0, 0, 0); } \
    __builtin_amdgcn_s_setprio(0); }

    bf16x8 af[8], bf[2];
    f32x4 acc[8][4] = {};
    const int NT = TWOD / GBK;   // 32 K-tiles
    const int NI = NT / 2;       // 16 iterations

    // prologue: tile0 (all 4 halves -> d0), tile1 k0 -> d1 = 12 loads.
    STG(0, 0, 0, 0); STG(1, 0, 0, 0); STG(0, 0, 1, 0); STG(1, 0, 1, 0);
    STG(0, 1, 0, 1); STG(1, 1, 0, 1);
    VMC4;   // confirm tile0 (8 oldest); tile1.k0 may fly until P4's ckpt
    BARR;

#pragma unroll 1
    for (int it = 0; it < NI; ++it) {
        const int t1 = 2 * it + 1, t2 = 2 * it + 2, t3 = 2 * it + 3;
        const bool lastI = (it == NI - 1);
        // P1: d0.k0, C-left
        RDA8(0, 0); RDB2(0, 0, 0); STG(0, t1, 1, 1);
        BARR; LGKM0; MFMA16(0); BARR;
        // P2: d0.k0, C-right
        RDB2(0, 0, 1); STG(1, t1, 1, 1);
        BARR; LGKM0; MFMA16(1); BARR;
        // P3: d0.k1, C-left
        RDA8(0, 1); RDB2(0, 1, 0); if (!lastI) STG(0, t2, 0, 0);
        BARR; LGKM0; MFMA16(0); BARR;
        // P4: d0.k1, C-right  + checkpoint
        RDB2(0, 1, 1); if (!lastI) STG(1, t2, 0, 0);
        BARR; LGKM0; MFMA16(1);
        if (lastI) { VMC0; } else { VMC4; }
        BARR;
        // P5: d1.k0, C-left
        RDA8(1, 0); RDB2(1, 0, 0); if (!lastI) STG(0, t2, 1, 0);
        BARR; LGKM0; MFMA16(0); BARR;
        // P6: d1.k0, C-right
        RDB2(1, 0, 1); if (!lastI) STG(1, t2, 1, 0);
        BARR; LGKM0; MFMA16(1); BARR;
        // P7: d1.k1, C-left
        RDA8(1, 1); RDB2(1, 1, 0); if (!lastI) STG(0, t3, 0, 1);
        BARR; LGKM0; MFMA16(0); BARR;
        // P8: d1.k1, C-right + checkpoint
        RDB2(1, 1, 1); if (!lastI) STG(1, t3, 0, 1);
        BARR; LGKM0; MFMA16(1);
        VMC4;
        BARR;
    }

    // epilogue: D col = lane&15, row = (lane>>4)*4 + reg  [verified m89/m91]
#pragma unroll
    for (int n = 0; n < 4; ++n) {
        const int col = n0 + wn * 64 + n * 16 + r16;
        const float bc = bias[col];
#pragma unroll
        for (int m = 0; m < 8; ++m) {
#pragma unroll
            for (int rg = 0; rg < 4; ++rg) {
                const size_t row = m0 + wm * 128 + m * 16 + q * 4 + rg;
                const float v = acc[m][n][rg] + bc;
                if (EPI == 0) {
                    if (n0 < DDIM) {
                        const float rr = 1.0f / (1.0f + __expf(-v));
                        const size_t idx = row * DDIM + col;
                        hr[idx] = f2bf(h[idx] * rr);
                    } else {
                        const float zz = 1.0f / (1.0f + __expf(-v));
                        zbuf[row * DDIM + (col - DDIM)] = zz;
                    }
                } else {
                    const float u = tanhf(v);
                    const size_t idx = row * DDIM + col;
                    const float zz = zbuf[idx];
                    const float hv = h[idx];
                    outp[idx] = hv * zz + (1.0f - zz) * u;
                }
            }
        }
    }
#undef RG
#undef STG
#undef BARR
#undef LGKM0
#undef VMC4
#undef VMC0
#undef RDA8
#undef RDB2
#undef MFMA16
}

// --------------------------------------------------------------------------
extern "C" void kernel_launch(void* const* d_in, const int* in_sizes, int n_in,
                              void* d_out, int out_size, void* d_ws, size_t ws_size,
                              hipStream_t stream) {
    const float* x  = (const float*)d_in[0];
    const float* h  = (const float*)d_in[1];
    const float* Wg = (const float*)d_in[2];
    const float* bg = (const float*)d_in[3];
    const float* Wu = (const float*)d_in[4];
    const float* bu = (const float*)d_in[5];
    const float* g1 = (const float*)d_in[6];
    const float* b1 = (const float*)d_in[7];
    const float* g2 = (const float*)d_in[8];
    const float* b2 = (const float*)d_in[9];
    const float* dm = (const float*)d_in[10];
    float* out = (float*)d_out;

    char* ws = (char*)d_ws;
    unsigned short* WgT = (unsigned short*)(ws);                    // 8 MB
    unsigned short* WuT = (unsigned short*)(ws + 8388608);          // 4 MB
    unsigned short* ln  = (unsigned short*)(ws + 12582912);         // 64 MB
    unsigned short* hr  = (unsigned short*)(ws + 79691776);         // 32 MB

    // allow 128KB dynamic LDS (host-side attr, graph-capture safe)
    hipFuncSetAttribute((const void*)gemm8p<0>,
                        hipFuncAttributeMaxDynamicSharedMemorySize, 131072);
    hipFuncSetAttribute((const void*)gemm8p<1>,
                        hipFuncAttributeMaxDynamicSharedMemorySize, 131072);

    wtrans<<<dim3(64, 64), 256, 0, stream>>>(Wg, WgT, TWOD, TWOD);
    wtrans<<<dim3(64, 32), 256, 0, stream>>>(Wu, WuT, TWOD, DDIM);
    ln_kernel<false><<<BATCH, 256, 0, stream>>>(x, (const void*)h, g1, b1, dm, ln);
    gemm8p<0><<<dim3(64, 8), NTH, 131072, stream>>>(ln, WgT, bg, h, hr, out, nullptr);
    ln_kernel<true><<<BATCH, 256, 0, stream>>>(x, (const void*)hr, g2, b2, dm, ln);
    gemm8p<1><<<dim3(64, 4), NTH, 131072, stream>>>(ln, WuT, bu, h, nullptr, out, out);
}

// Round 7
// 460.993 us; speedup vs baseline: 1.0135x; 1.0135x over previous
//
#include <hip/hip_runtime.h>
#include <hip/hip_bf16.h>

// GRUCell fused cell. B=16384, d=1024, 2d=2048.
//   inp  = LN(concat(x,h); g1,b1) * dm
//   gates= inp @ Wg + bg ; r=sig(gates[:, :d]); z=sig(gates[:, d:])
//   inp2 = LN(concat(x, h*r); g2,b2) * dm
//   u    = tanh(inp2 @ Wu + bu)
//   out  = h*z + (1-z)*u
//
// R7: occupancy-first GEMM redesign. 128x128 tile, BK=32, 4 waves, 3-slot
// LDS ring (48KB static -> 3 blocks/CU, ~12 waves/CU). All prior rounds ran
// 1 block/CU (8 waves sharing one barrier set) and pinned at ~600 TF
// regardless of schedule; m97/m114 data says cross-block wave overlap at
// ~3 blocks/CU is the missing latency-hiding. Counted vmcnt(4) boundary
// (stage 2 tiles ahead), granule-XOR swizzle (PMC-verified 0 conflicts).
//
// Ring safety: body T = {vmcnt; barrier; read frags(T); stage(T+2); MFMA}.
// After barrier T all waves' tile-(T-1) frag reads are complete (their MFMAs
// executed before barrier T, compiler lgkmcnt before use). stage(T+2)
// overwrites slot((T+2)%3) = slot of T-1. Reads of T confirmed: at body T's
// wait, outstanding = stage(T) [body T-2 or prologue] + stage(T+1) [body
// T-1] = 8 loads; vmcnt(4) retires the oldest 4 = stage(T). Last body uses
// vmcnt(0) (nothing newer in flight).
//
// ws layout (bytes):
//   [0,            8388608)  WgT  bf16 [2048][2048]  (WgT[n][k] = Wg[k][n])
//   [8388608,     12582912)  WuT  bf16 [1024][2048]
//   [12582912,    79691776)  ln   bf16 [16384][2048] (LN1 then LN2 output)
//   [79691776,   113246208)  hr   bf16 [16384][1024] (h * r)
// z (f32) staged in d_out between GEMM1 and GEMM2 (each element read only by
// the thread that overwrites it in GEMM2's epilogue).

#define BATCH 16384
#define DDIM  1024
#define TWOD  2048
#define LNEPS 1e-5f

#define GBK 32
#define NTH 256

typedef __bf16 bf16x8 __attribute__((ext_vector_type(8)));
typedef float  f32x4  __attribute__((ext_vector_type(4)));
typedef unsigned short ushort4v __attribute__((ext_vector_type(4)));

__device__ __forceinline__ unsigned short f2bf(float f) {
    unsigned int u = __builtin_bit_cast(unsigned int, f);
    u = (u + 0x7FFFu + ((u >> 16) & 1u)) >> 16;   // round-to-nearest-even
    return (unsigned short)u;
}
__device__ __forceinline__ float bf2f(unsigned short s) {
    unsigned int u = ((unsigned int)s) << 16;
    return __builtin_bit_cast(float, u);
}
__device__ __forceinline__ void gload16(const void* g, void* l) {
    __builtin_amdgcn_global_load_lds((__attribute__((address_space(1))) void*)(g),
                                     (__attribute__((address_space(3))) void*)(l),
                                     16u, 0, 0);
}

// ---------------- weight transpose + f32->bf16 cast ------------------------
__global__ __launch_bounds__(256) void wtrans(const float* __restrict__ W,
                                              unsigned short* __restrict__ WT,
                                              int K, int N) {
    __shared__ float tile[32][33];
    const int k0 = blockIdx.x * 32;
    const int n0 = blockIdx.y * 32;
    const int tx = threadIdx.x & 31;
    const int ty = threadIdx.x >> 5;
#pragma unroll
    for (int p = 0; p < 32; p += 8)
        tile[p + ty][tx] = W[(size_t)(k0 + p + ty) * N + n0 + tx];
    __syncthreads();
#pragma unroll
    for (int p = 0; p < 32; p += 8)
        WT[(size_t)(n0 + p + ty) * K + k0 + tx] = f2bf(tile[tx][p + ty]);
}

// ---------------- fused LayerNorm over concat(x, second) -------------------
template <bool SECOND_BF16>
__global__ __launch_bounds__(256) void ln_kernel(const float* __restrict__ x,
                                                 const void* __restrict__ h2,
                                                 const float* __restrict__ g,
                                                 const float* __restrict__ bt,
                                                 const float* __restrict__ dm,
                                                 unsigned short* __restrict__ out) {
    const int row  = blockIdx.x;
    const int tid  = threadIdx.x;
    const int lane = tid & 63;
    const int w    = tid >> 6;

    const float4 xl = reinterpret_cast<const float4*>(x + (size_t)row * DDIM)[tid];
    float hv[4];
    if (SECOND_BF16) {
        const ushort4v hl = reinterpret_cast<const ushort4v*>(
            (const unsigned short*)h2 + (size_t)row * DDIM)[tid];
#pragma unroll
        for (int j = 0; j < 4; ++j) hv[j] = bf2f(hl[j]);
    } else {
        const float4 hl = reinterpret_cast<const float4*>(
            (const float*)h2 + (size_t)row * DDIM)[tid];
        hv[0] = hl.x; hv[1] = hl.y; hv[2] = hl.z; hv[3] = hl.w;
    }
    float xv[4] = {xl.x, xl.y, xl.z, xl.w};

    float s = 0.f, ss = 0.f;
#pragma unroll
    for (int j = 0; j < 4; ++j) { s += xv[j] + hv[j]; ss += xv[j]*xv[j] + hv[j]*hv[j]; }
#pragma unroll
    for (int o = 32; o; o >>= 1) { s += __shfl_xor(s, o); ss += __shfl_xor(ss, o); }
    __shared__ float red[8];
    if (lane == 0) { red[w] = s; red[4 + w] = ss; }
    __syncthreads();
    s  = red[0] + red[1] + red[2] + red[3];
    ss = red[4] + red[5] + red[6] + red[7];
    const float inv  = 1.0f / (float)TWOD;
    const float mu   = s * inv;
    const float var  = ss * inv - mu * mu;
    const float rstd = rsqrtf(var + LNEPS);

    {
        const float4 gv = reinterpret_cast<const float4*>(g)[tid];
        const float4 bv = reinterpret_cast<const float4*>(bt)[tid];
        const float4 dv = reinterpret_cast<const float4*>(dm)[tid];
        ushort4v pk;
        pk[0] = f2bf(((xv[0] - mu) * rstd * gv.x + bv.x) * dv.x);
        pk[1] = f2bf(((xv[1] - mu) * rstd * gv.y + bv.y) * dv.y);
        pk[2] = f2bf(((xv[2] - mu) * rstd * gv.z + bv.z) * dv.z);
        pk[3] = f2bf(((xv[3] - mu) * rstd * gv.w + bv.w) * dv.w);
        reinterpret_cast<ushort4v*>(out + (size_t)row * TWOD)[tid] = pk;
    }
    {
        const float4 gv = reinterpret_cast<const float4*>(g)[256 + tid];
        const float4 bv = reinterpret_cast<const float4*>(bt)[256 + tid];
        const float4 dv = reinterpret_cast<const float4*>(dm)[256 + tid];
        ushort4v pk;
        pk[0] = f2bf(((hv[0] - mu) * rstd * gv.x + bv.x) * dv.x);
        pk[1] = f2bf(((hv[1] - mu) * rstd * gv.y + bv.y) * dv.y);
        pk[2] = f2bf(((hv[2] - mu) * rstd * gv.z + bv.z) * dv.z);
        pk[3] = f2bf(((hv[3] - mu) * rstd * gv.w + bv.w) * dv.w);
        reinterpret_cast<ushort4v*>(out + (size_t)row * TWOD + DDIM)[tid] = pk;
    }
}

// ---------------- 128x128 4-wave 3-block/CU bf16 GEMM ----------------------
// A : [16384][2048] bf16 row-major (LN output)
// BT: [N][2048]     bf16 row-major (transposed weights)
// LDS: 3-slot ring, slot = 16KB = As[128][32] + Bs[128][32] bf16.
//   Granule = 16B (8 bf16); row = 4 granules. Phys granule = logical ^
//   ((row>>1)&3). global_load_lds dest linear, SOURCE pre-swizzled.
template <int EPI>
__global__ __launch_bounds__(NTH, 3) void gemm128(const unsigned short* __restrict__ A,
                                                  const unsigned short* __restrict__ BT,
                                                  const float* __restrict__ bias,
                                                  const float* __restrict__ h,
                                                  unsigned short* __restrict__ hr,
                                                  float* __restrict__ zbuf,
                                                  float* __restrict__ outp) {
    __shared__ char sm[49152];        // 3 x 16KB slots
    const int tid  = threadIdx.x;
    const int lane = tid & 63;
    const int w    = tid >> 6;        // 0..3
    const int wm   = w >> 1;          // 0..1 (M-warp)
    const int wn   = w & 1;           // 0..1 (N-warp)
    const int q    = lane >> 4;       // 0..3 (K-chunk)
    const int r16  = lane & 15;
    const size_t m0 = (size_t)blockIdx.x * 128;
    const int    n0 = blockIdx.y * 128;

    const unsigned short* Ag = A  + m0 * TWOD;
    const unsigned short* Bg = BT + (size_t)n0 * TWOD;

    // staging: 128x32 tile = 512 granules; thread t covers granules t, t+256.
    // rows rg0 and rg0+64 share the same swizzle index ((rg>>1)&3 invariant).
    const int rg0 = tid >> 2;                        // 0..63
    const int sg  = (tid & 3) ^ ((rg0 >> 1) & 3);
    const unsigned short* a0 = Ag + (size_t)rg0 * TWOD + sg * 8;
    const unsigned short* a1 = Ag + (size_t)(rg0 + 64) * TWOD + sg * 8;
    const unsigned short* b0 = Bg + (size_t)rg0 * TWOD + sg * 8;
    const unsigned short* b1 = Bg + (size_t)(rg0 + 64) * TWOD + sg * 8;
    const unsigned dA0 = (unsigned)w * 1024u;        // gload dest: +lane*16 by HW

#define STAGE(t, slot) { char* s_ = sm + (unsigned)(slot) * 16384u; \
    const int k_ = (t) * GBK; \
    gload16(a0 + k_, s_ + dA0); \
    gload16(a1 + k_, s_ + dA0 + 4096u); \
    gload16(b0 + k_, s_ + 8192u + dA0); \
    gload16(b1 + k_, s_ + 8192u + dA0 + 4096u); }

    // frag-read offsets (phys granule = q ^ ((r16>>1)&3); row-parity trick:
    // rows are base16k + r16 so (row>>1)&3 == (r16>>1)&3)
    const unsigned pgo  = (unsigned)((q ^ ((r16 >> 1) & 3)) * 16);
    const unsigned arow = (unsigned)((wm * 64 + r16) * 64) + pgo;           // + i*1024
    const unsigned brow = 8192u + (unsigned)((wn * 64 + r16) * 64) + pgo;   // + n*1024

    f32x4 acc[4][4] = {};
    const int NT = TWOD / GBK;   // 64

    // prologue: tiles 0,1 in flight (8 loads/thread)
    STAGE(0, 0); STAGE(1, 1);

    int rs = 0, ssl = 2;   // read slot of T, stage slot of T+2
#pragma unroll 1
    for (int T = 0; T < NT; ++T) {
        if (T < NT - 1) { asm volatile("s_waitcnt vmcnt(4)" ::: "memory"); }
        else            { asm volatile("s_waitcnt vmcnt(0)" ::: "memory"); }
        asm volatile("s_barrier" ::: "memory");

        const unsigned sb = (unsigned)rs * 16384u;
        bf16x8 af[4], bf[4];
#pragma unroll
        for (int n = 0; n < 4; ++n)
            bf[n] = *(const bf16x8*)(sm + sb + brow + (unsigned)n * 1024u);
#pragma unroll
        for (int i = 0; i < 4; ++i)
            af[i] = *(const bf16x8*)(sm + sb + arow + (unsigned)i * 1024u);
        if (T + 2 < NT) STAGE(T + 2, ssl);
        __builtin_amdgcn_s_setprio(1);
#pragma unroll
        for (int i = 0; i < 4; ++i)
#pragma unroll
            for (int n = 0; n < 4; ++n)
                acc[i][n] = __builtin_amdgcn_mfma_f32_16x16x32_bf16(af[i], bf[n], acc[i][n], 0, 0, 0);
        __builtin_amdgcn_s_setprio(0);
        rs  = (rs  == 2) ? 0 : rs + 1;
        ssl = (ssl == 2) ? 0 : ssl + 1;
    }

    // epilogue: D col = lane&15, row = (lane>>4)*4 + reg  [verified m89/m91]
#pragma unroll
    for (int n = 0; n < 4; ++n) {
        const int col = n0 + wn * 64 + n * 16 + r16;
        const float bc = bias[col];
#pragma unroll
        for (int m = 0; m < 4; ++m) {
#pragma unroll
            for (int rg = 0; rg < 4; ++rg) {
                const size_t row = m0 + wm * 64 + m * 16 + q * 4 + rg;
                const float v = acc[m][n][rg] + bc;
                if (EPI == 0) {
                    if (n0 < DDIM) {
                        const float rr = 1.0f / (1.0f + __expf(-v));
                        const size_t idx = row * DDIM + col;
                        hr[idx] = f2bf(h[idx] * rr);
                    } else {
                        const float zz = 1.0f / (1.0f + __expf(-v));
                        zbuf[row * DDIM + (col - DDIM)] = zz;
                    }
                } else {
                    const float u = tanhf(v);
                    const size_t idx = row * DDIM + col;
                    const float zz = zbuf[idx];
                    const float hv = h[idx];
                    outp[idx] = hv * zz + (1.0f - zz) * u;
                }
            }
        }
    }
#undef STAGE
}

// --------------------------------------------------------------------------
extern "C" void kernel_launch(void* const* d_in, const int* in_sizes, int n_in,
                              void* d_out, int out_size, void* d_ws, size_t ws_size,
                              hipStream_t stream) {
    const float* x  = (const float*)d_in[0];
    const float* h  = (const float*)d_in[1];
    const float* Wg = (const float*)d_in[2];
    const float* bg = (const float*)d_in[3];
    const float* Wu = (const float*)d_in[4];
    const float* bu = (const float*)d_in[5];
    const float* g1 = (const float*)d_in[6];
    const float* b1 = (const float*)d_in[7];
    const float* g2 = (const float*)d_in[8];
    const float* b2 = (const float*)d_in[9];
    const float* dm = (const float*)d_in[10];
    float* out = (float*)d_out;

    char* ws = (char*)d_ws;
    unsigned short* WgT = (unsigned short*)(ws);                    // 8 MB
    unsigned short* WuT = (unsigned short*)(ws + 8388608);          // 4 MB
    unsigned short* ln  = (unsigned short*)(ws + 12582912);         // 64 MB
    unsigned short* hr  = (unsigned short*)(ws + 79691776);         // 32 MB

    wtrans<<<dim3(64, 64), 256, 0, stream>>>(Wg, WgT, TWOD, TWOD);
    wtrans<<<dim3(64, 32), 256, 0, stream>>>(Wu, WuT, TWOD, DDIM);
    ln_kernel<false><<<BATCH, 256, 0, stream>>>(x, (const void*)h, g1, b1, dm, ln);
    gemm128<0><<<dim3(128, 16), NTH, 0, stream>>>(ln, WgT, bg, h, hr, out, nullptr);
    ln_kernel<true><<<BATCH, 256, 0, stream>>>(x, (const void*)hr, g2, b2, dm, ln);
    gemm128<1><<<dim3(128, 8), NTH, 0, stream>>>(ln, WuT, bu, h, nullptr, out, out);
}

// Round 8
// 433.912 us; speedup vs baseline: 1.0767x; 1.0624x over previous
//
#include <hip/hip_runtime.h>
#include <hip/hip_bf16.h>

// GRUCell fused cell. B=16384, d=1024, 2d=2048.
//   inp  = LN(concat(x,h); g1,b1) * dm
//   gates= inp @ Wg + bg ; r=sig(gates[:, :d]); z=sig(gates[:, d:])
//   inp2 = LN(concat(x, h*r); g2,b2) * dm
//   u    = tanh(inp2 @ Wu + bu)
//   out  = h*z + (1-z)*u
//
// R8: m97-clone GEMM (the structure HW-measured at 874-912 TF on this
// geometry): 128x128 tile, BK=32, 4 waves, SINGLE 16KB buffer, two
// __syncthreads per K-step, NO setprio, NO manual waitcnt, NO ring.
// R2-R7's schedules (setprio + counted vmcnt + rings) all pinned at
// ~600 TF; m190 says setprio HURTS lockstep GEMM, m114 says cross-block
// wave overlap at ~3 blk/CU is what m97's perf actually rides on.
// Kept from R7: granule-XOR swizzle pair (PMC-verified 0 conflicts).
// Added: XCD-aware chunked block swizzle (T1), y-fastest decode -> all
// N-blocks of an A-panel run consecutively on one XCD (A-panel 0.5MB
// L2-resident; attacks the 400MB refetch R7 exposed).
//
// ws layout (bytes):
//   [0,            8388608)  WgT  bf16 [2048][2048]  (WgT[n][k] = Wg[k][n])
//   [8388608,     12582912)  WuT  bf16 [1024][2048]
//   [12582912,    79691776)  ln   bf16 [16384][2048] (LN1 then LN2 output)
//   [79691776,   113246208)  hr   bf16 [16384][1024] (h * r)
// z (f32) staged in d_out between GEMM1 and GEMM2 (each element read only by
// the thread that overwrites it in GEMM2's epilogue).

#define BATCH 16384
#define DDIM  1024
#define TWOD  2048
#define LNEPS 1e-5f

#define GBK 32
#define NTH 256

typedef __bf16 bf16x8 __attribute__((ext_vector_type(8)));
typedef float  f32x4  __attribute__((ext_vector_type(4)));
typedef unsigned short ushort4v __attribute__((ext_vector_type(4)));

__device__ __forceinline__ unsigned short f2bf(float f) {
    unsigned int u = __builtin_bit_cast(unsigned int, f);
    u = (u + 0x7FFFu + ((u >> 16) & 1u)) >> 16;   // round-to-nearest-even
    return (unsigned short)u;
}
__device__ __forceinline__ float bf2f(unsigned short s) {
    unsigned int u = ((unsigned int)s) << 16;
    return __builtin_bit_cast(float, u);
}
__device__ __forceinline__ void gload16(const void* g, void* l) {
    __builtin_amdgcn_global_load_lds((__attribute__((address_space(1))) void*)(g),
                                     (__attribute__((address_space(3))) void*)(l),
                                     16u, 0, 0);
}

// ---------------- weight transpose + f32->bf16 cast ------------------------
__global__ __launch_bounds__(256) void wtrans(const float* __restrict__ W,
                                              unsigned short* __restrict__ WT,
                                              int K, int N) {
    __shared__ float tile[32][33];
    const int k0 = blockIdx.x * 32;
    const int n0 = blockIdx.y * 32;
    const int tx = threadIdx.x & 31;
    const int ty = threadIdx.x >> 5;
#pragma unroll
    for (int p = 0; p < 32; p += 8)
        tile[p + ty][tx] = W[(size_t)(k0 + p + ty) * N + n0 + tx];
    __syncthreads();
#pragma unroll
    for (int p = 0; p < 32; p += 8)
        WT[(size_t)(n0 + p + ty) * K + k0 + tx] = f2bf(tile[tx][p + ty]);
}

// ---------------- fused LayerNorm over concat(x, second) -------------------
template <bool SECOND_BF16>
__global__ __launch_bounds__(256) void ln_kernel(const float* __restrict__ x,
                                                 const void* __restrict__ h2,
                                                 const float* __restrict__ g,
                                                 const float* __restrict__ bt,
                                                 const float* __restrict__ dm,
                                                 unsigned short* __restrict__ out) {
    const int row  = blockIdx.x;
    const int tid  = threadIdx.x;
    const int lane = tid & 63;
    const int w    = tid >> 6;

    const float4 xl = reinterpret_cast<const float4*>(x + (size_t)row * DDIM)[tid];
    float hv[4];
    if (SECOND_BF16) {
        const ushort4v hl = reinterpret_cast<const ushort4v*>(
            (const unsigned short*)h2 + (size_t)row * DDIM)[tid];
#pragma unroll
        for (int j = 0; j < 4; ++j) hv[j] = bf2f(hl[j]);
    } else {
        const float4 hl = reinterpret_cast<const float4*>(
            (const float*)h2 + (size_t)row * DDIM)[tid];
        hv[0] = hl.x; hv[1] = hl.y; hv[2] = hl.z; hv[3] = hl.w;
    }
    float xv[4] = {xl.x, xl.y, xl.z, xl.w};

    float s = 0.f, ss = 0.f;
#pragma unroll
    for (int j = 0; j < 4; ++j) { s += xv[j] + hv[j]; ss += xv[j]*xv[j] + hv[j]*hv[j]; }
#pragma unroll
    for (int o = 32; o; o >>= 1) { s += __shfl_xor(s, o); ss += __shfl_xor(ss, o); }
    __shared__ float red[8];
    if (lane == 0) { red[w] = s; red[4 + w] = ss; }
    __syncthreads();
    s  = red[0] + red[1] + red[2] + red[3];
    ss = red[4] + red[5] + red[6] + red[7];
    const float inv  = 1.0f / (float)TWOD;
    const float mu   = s * inv;
    const float var  = ss * inv - mu * mu;
    const float rstd = rsqrtf(var + LNEPS);

    {
        const float4 gv = reinterpret_cast<const float4*>(g)[tid];
        const float4 bv = reinterpret_cast<const float4*>(bt)[tid];
        const float4 dv = reinterpret_cast<const float4*>(dm)[tid];
        ushort4v pk;
        pk[0] = f2bf(((xv[0] - mu) * rstd * gv.x + bv.x) * dv.x);
        pk[1] = f2bf(((xv[1] - mu) * rstd * gv.y + bv.y) * dv.y);
        pk[2] = f2bf(((xv[2] - mu) * rstd * gv.z + bv.z) * dv.z);
        pk[3] = f2bf(((xv[3] - mu) * rstd * gv.w + bv.w) * dv.w);
        reinterpret_cast<ushort4v*>(out + (size_t)row * TWOD)[tid] = pk;
    }
    {
        const float4 gv = reinterpret_cast<const float4*>(g)[256 + tid];
        const float4 bv = reinterpret_cast<const float4*>(bt)[256 + tid];
        const float4 dv = reinterpret_cast<const float4*>(dm)[256 + tid];
        ushort4v pk;
        pk[0] = f2bf(((hv[0] - mu) * rstd * gv.x + bv.x) * dv.x);
        pk[1] = f2bf(((hv[1] - mu) * rstd * gv.y + bv.y) * dv.y);
        pk[2] = f2bf(((hv[2] - mu) * rstd * gv.z + bv.z) * dv.z);
        pk[3] = f2bf(((hv[3] - mu) * rstd * gv.w + bv.w) * dv.w);
        reinterpret_cast<ushort4v*>(out + (size_t)row * TWOD + DDIM)[tid] = pk;
    }
}

// ---------------- m97-clone 128x128 bf16 GEMM ------------------------------
// A : [16384][2048] bf16 row-major (LN output)
// BT: [N][2048]     bf16 row-major (transposed weights)
// Single 16KB buffer (As 8KB + Bs 8KB), two __syncthreads per K-step.
// Granule-XOR swizzle pair: stage source pre-swizzled (phys granule =
// logical ^ ((row>>1)&3)), frag reads apply the same XOR -> 0 conflicts.
// Grid: 1D, XCD-chunk swizzled; decode y-fastest (A-panel locality per XCD).
template <int EPI>
__global__ __launch_bounds__(NTH, 3) void gemm97(const unsigned short* __restrict__ A,
                                                 const unsigned short* __restrict__ BT,
                                                 const float* __restrict__ bias,
                                                 const float* __restrict__ h,
                                                 unsigned short* __restrict__ hr,
                                                 float* __restrict__ zbuf,
                                                 float* __restrict__ outp,
                                                 int NYB) {
    __shared__ unsigned short As[4096];   // [128][32] bf16, 8KB
    __shared__ unsigned short Bs[4096];
    const int tid  = threadIdx.x;
    const int lane = tid & 63;
    const int w    = tid >> 6;        // 0..3
    const int wm   = w >> 1;          // 0..1 (M-warp)
    const int wn   = w & 1;           // 0..1 (N-warp)
    const int q    = lane >> 4;       // 0..3 (K-chunk)
    const int r16  = lane & 15;

    // XCD-chunk swizzle (bijective: nwg % 8 == 0), y-fastest decode
    const int nwg = gridDim.x;
    const int cid = (blockIdx.x & 7) * (nwg >> 3) + (blockIdx.x >> 3);
    const size_t m0 = (size_t)(cid / NYB) * 128;
    const int    n0 = (cid % NYB) * 128;

    const unsigned short* Ag = A  + m0 * TWOD;
    const unsigned short* Bg = BT + (size_t)n0 * TWOD;

    // staging: 512 granules per operand; thread t covers granules t, t+256.
    // source column-granule pre-swizzled; LDS dest linear (HW: base+lane*16).
    const int rg0 = tid >> 2;                        // rows 0..63 (+64 for 2nd)
    const int sg  = (tid & 3) ^ ((rg0 >> 1) & 3);    // parity same for rg0+64
    const unsigned short* a0 = Ag + (size_t)rg0 * TWOD + sg * 8;
    const unsigned short* a1 = Ag + (size_t)(rg0 + 64) * TWOD + sg * 8;
    const unsigned short* b0 = Bg + (size_t)rg0 * TWOD + sg * 8;
    const unsigned short* b1 = Bg + (size_t)(rg0 + 64) * TWOD + sg * 8;
    const unsigned dst = (unsigned)w * 1024u;        // + lane*16 by HW

    // frag-read offsets: phys granule = q ^ ((r16>>1)&3) (row-parity trick)
    const unsigned pgo  = (unsigned)((q ^ ((r16 >> 1) & 3)) * 16);
    const unsigned arow = (unsigned)((wm * 64 + r16) * 64) + pgo;   // + i*1024
    const unsigned brow = (unsigned)((wn * 64 + r16) * 64) + pgo;   // + n*1024

    f32x4 acc[4][4] = {};
    const int NT = TWOD / GBK;   // 64

    for (int T = 0; T < NT; ++T) {
        const int k_ = T * GBK;
        gload16(a0 + k_, (char*)As + dst);
        gload16(a1 + k_, (char*)As + dst + 4096u);
        gload16(b0 + k_, (char*)Bs + dst);
        gload16(b1 + k_, (char*)Bs + dst + 4096u);
        __syncthreads();                 // full drain (m97 semantics)
        bf16x8 af[4], bf[4];
#pragma unroll
        for (int n = 0; n < 4; ++n)
            bf[n] = *(const bf16x8*)((const char*)Bs + brow + (unsigned)n * 1024u);
#pragma unroll
        for (int i = 0; i < 4; ++i)
            af[i] = *(const bf16x8*)((const char*)As + arow + (unsigned)i * 1024u);
#pragma unroll
        for (int i = 0; i < 4; ++i)
#pragma unroll
            for (int n = 0; n < 4; ++n)
                acc[i][n] = __builtin_amdgcn_mfma_f32_16x16x32_bf16(af[i], bf[n], acc[i][n], 0, 0, 0);
        __syncthreads();
    }

    // epilogue: D col = lane&15, row = (lane>>4)*4 + reg  [verified m89/m91]
#pragma unroll
    for (int n = 0; n < 4; ++n) {
        const int col = n0 + wn * 64 + n * 16 + r16;
        const float bc = bias[col];
#pragma unroll
        for (int m = 0; m < 4; ++m) {
#pragma unroll
            for (int rg = 0; rg < 4; ++rg) {
                const size_t row = m0 + wm * 64 + m * 16 + q * 4 + rg;
                const float v = acc[m][n][rg] + bc;
                if (EPI == 0) {
                    if (n0 < DDIM) {
                        const float rr = 1.0f / (1.0f + __expf(-v));
                        const size_t idx = row * DDIM + col;
                        hr[idx] = f2bf(h[idx] * rr);
                    } else {
                        const float zz = 1.0f / (1.0f + __expf(-v));
                        zbuf[row * DDIM + (col - DDIM)] = zz;
                    }
                } else {
                    const float u = tanhf(v);
                    const size_t idx = row * DDIM + col;
                    const float zz = zbuf[idx];
                    const float hv = h[idx];
                    outp[idx] = hv * zz + (1.0f - zz) * u;
                }
            }
        }
    }
}

// --------------------------------------------------------------------------
extern "C" void kernel_launch(void* const* d_in, const int* in_sizes, int n_in,
                              void* d_out, int out_size, void* d_ws, size_t ws_size,
                              hipStream_t stream) {
    const float* x  = (const float*)d_in[0];
    const float* h  = (const float*)d_in[1];
    const float* Wg = (const float*)d_in[2];
    const float* bg = (const float*)d_in[3];
    const float* Wu = (const float*)d_in[4];
    const float* bu = (const float*)d_in[5];
    const float* g1 = (const float*)d_in[6];
    const float* b1 = (const float*)d_in[7];
    const float* g2 = (const float*)d_in[8];
    const float* b2 = (const float*)d_in[9];
    const float* dm = (const float*)d_in[10];
    float* out = (float*)d_out;

    char* ws = (char*)d_ws;
    unsigned short* WgT = (unsigned short*)(ws);                    // 8 MB
    unsigned short* WuT = (unsigned short*)(ws + 8388608);          // 4 MB
    unsigned short* ln  = (unsigned short*)(ws + 12582912);         // 64 MB
    unsigned short* hr  = (unsigned short*)(ws + 79691776);         // 32 MB

    wtrans<<<dim3(64, 64), 256, 0, stream>>>(Wg, WgT, TWOD, TWOD);
    wtrans<<<dim3(64, 32), 256, 0, stream>>>(Wu, WuT, TWOD, DDIM);
    ln_kernel<false><<<BATCH, 256, 0, stream>>>(x, (const void*)h, g1, b1, dm, ln);
    // GEMM1: 128 M-blocks x 16 N-blocks = 2048 (div 8 ok)
    gemm97<0><<<2048, NTH, 0, stream>>>(ln, WgT, bg, h, hr, out, nullptr, 16);
    ln_kernel<true><<<BATCH, 256, 0, stream>>>(x, (const void*)hr, g2, b2, dm, ln);
    // GEMM2: 128 x 8 = 1024 (div 8 ok)
    gemm97<1><<<1024, NTH, 0, stream>>>(ln, WuT, bu, h, nullptr, out, out, 8);
}

// Round 9
// 384.790 us; speedup vs baseline: 1.2142x; 1.1277x over previous
//
#include <hip/hip_runtime.h>
#include <hip/hip_bf16.h>

// GRUCell fused cell. B=16384, d=1024, 2d=2048.
//   inp  = LN(concat(x,h); g1,b1) * dm
//   gates= inp @ Wg + bg ; r=sig(gates[:, :d]); z=sig(gates[:, d:])
//   inp2 = LN(concat(x, h*r); g2,b2) * dm
//   u    = tanh(inp2 @ Wu + bu)
//   out  = h*z + (1-z)*u
//
// R9 = R8 (m97-structure: single buffer, 2x __syncthreads/step, no setprio,
// no manual waitcnt, XCD chunk swizzle) but BK=64: halves the number of
// vmcnt(0)+barrier drains (the exposed ~900cyc load latency per K-step that
// R8's counters said dominates: MfmaUtil 23%, both GEMMs equal-duration).
// LDS 32KB/block keeps 3 blocks/CU. Frags read per-sub-k (8 live) to keep
// VGPR low. Swizzle for 128B rows: phys_colgranule = logical ^ (row&7);
// stage source pre-XORed, LDS dest linear, read applies same XOR.
//
// ws layout (bytes):
//   [0,            8388608)  WgT  bf16 [2048][2048]  (WgT[n][k] = Wg[k][n])
//   [8388608,     12582912)  WuT  bf16 [1024][2048]
//   [12582912,    79691776)  ln   bf16 [16384][2048] (LN1 then LN2 output)
//   [79691776,   113246208)  hr   bf16 [16384][1024] (h * r)
// z (f32) staged in d_out between GEMM1 and GEMM2 (each element read only by
// the thread that overwrites it in GEMM2's epilogue).

#define BATCH 16384
#define DDIM  1024
#define TWOD  2048
#define LNEPS 1e-5f

#define GBK 64
#define NTH 256

typedef __bf16 bf16x8 __attribute__((ext_vector_type(8)));
typedef float  f32x4  __attribute__((ext_vector_type(4)));
typedef unsigned short ushort4v __attribute__((ext_vector_type(4)));

__device__ __forceinline__ unsigned short f2bf(float f) {
    unsigned int u = __builtin_bit_cast(unsigned int, f);
    u = (u + 0x7FFFu + ((u >> 16) & 1u)) >> 16;   // round-to-nearest-even
    return (unsigned short)u;
}
__device__ __forceinline__ float bf2f(unsigned short s) {
    unsigned int u = ((unsigned int)s) << 16;
    return __builtin_bit_cast(float, u);
}
__device__ __forceinline__ void gload16(const void* g, void* l) {
    __builtin_amdgcn_global_load_lds((__attribute__((address_space(1))) void*)(g),
                                     (__attribute__((address_space(3))) void*)(l),
                                     16u, 0, 0);
}

// ---------------- weight transpose + f32->bf16 cast ------------------------
__global__ __launch_bounds__(256) void wtrans(const float* __restrict__ W,
                                              unsigned short* __restrict__ WT,
                                              int K, int N) {
    __shared__ float tile[32][33];
    const int k0 = blockIdx.x * 32;
    const int n0 = blockIdx.y * 32;
    const int tx = threadIdx.x & 31;
    const int ty = threadIdx.x >> 5;
#pragma unroll
    for (int p = 0; p < 32; p += 8)
        tile[p + ty][tx] = W[(size_t)(k0 + p + ty) * N + n0 + tx];
    __syncthreads();
#pragma unroll
    for (int p = 0; p < 32; p += 8)
        WT[(size_t)(n0 + p + ty) * K + k0 + tx] = f2bf(tile[tx][p + ty]);
}

// ---------------- fused LayerNorm over concat(x, second) -------------------
template <bool SECOND_BF16>
__global__ __launch_bounds__(256) void ln_kernel(const float* __restrict__ x,
                                                 const void* __restrict__ h2,
                                                 const float* __restrict__ g,
                                                 const float* __restrict__ bt,
                                                 const float* __restrict__ dm,
                                                 unsigned short* __restrict__ out) {
    const int row  = blockIdx.x;
    const int tid  = threadIdx.x;
    const int lane = tid & 63;
    const int w    = tid >> 6;

    const float4 xl = reinterpret_cast<const float4*>(x + (size_t)row * DDIM)[tid];
    float hv[4];
    if (SECOND_BF16) {
        const ushort4v hl = reinterpret_cast<const ushort4v*>(
            (const unsigned short*)h2 + (size_t)row * DDIM)[tid];
#pragma unroll
        for (int j = 0; j < 4; ++j) hv[j] = bf2f(hl[j]);
    } else {
        const float4 hl = reinterpret_cast<const float4*>(
            (const float*)h2 + (size_t)row * DDIM)[tid];
        hv[0] = hl.x; hv[1] = hl.y; hv[2] = hl.z; hv[3] = hl.w;
    }
    float xv[4] = {xl.x, xl.y, xl.z, xl.w};

    float s = 0.f, ss = 0.f;
#pragma unroll
    for (int j = 0; j < 4; ++j) { s += xv[j] + hv[j]; ss += xv[j]*xv[j] + hv[j]*hv[j]; }
#pragma unroll
    for (int o = 32; o; o >>= 1) { s += __shfl_xor(s, o); ss += __shfl_xor(ss, o); }
    __shared__ float red[8];
    if (lane == 0) { red[w] = s; red[4 + w] = ss; }
    __syncthreads();
    s  = red[0] + red[1] + red[2] + red[3];
    ss = red[4] + red[5] + red[6] + red[7];
    const float inv  = 1.0f / (float)TWOD;
    const float mu   = s * inv;
    const float var  = ss * inv - mu * mu;
    const float rstd = rsqrtf(var + LNEPS);

    {
        const float4 gv = reinterpret_cast<const float4*>(g)[tid];
        const float4 bv = reinterpret_cast<const float4*>(bt)[tid];
        const float4 dv = reinterpret_cast<const float4*>(dm)[tid];
        ushort4v pk;
        pk[0] = f2bf(((xv[0] - mu) * rstd * gv.x + bv.x) * dv.x);
        pk[1] = f2bf(((xv[1] - mu) * rstd * gv.y + bv.y) * dv.y);
        pk[2] = f2bf(((xv[2] - mu) * rstd * gv.z + bv.z) * dv.z);
        pk[3] = f2bf(((xv[3] - mu) * rstd * gv.w + bv.w) * dv.w);
        reinterpret_cast<ushort4v*>(out + (size_t)row * TWOD)[tid] = pk;
    }
    {
        const float4 gv = reinterpret_cast<const float4*>(g)[256 + tid];
        const float4 bv = reinterpret_cast<const float4*>(bt)[256 + tid];
        const float4 dv = reinterpret_cast<const float4*>(dm)[256 + tid];
        ushort4v pk;
        pk[0] = f2bf(((hv[0] - mu) * rstd * gv.x + bv.x) * dv.x);
        pk[1] = f2bf(((hv[1] - mu) * rstd * gv.y + bv.y) * dv.y);
        pk[2] = f2bf(((hv[2] - mu) * rstd * gv.z + bv.z) * dv.z);
        pk[3] = f2bf(((hv[3] - mu) * rstd * gv.w + bv.w) * dv.w);
        reinterpret_cast<ushort4v*>(out + (size_t)row * TWOD + DDIM)[tid] = pk;
    }
}

// ---------------- 128x128 BK=64 m97-structure bf16 GEMM --------------------
// A : [16384][2048] bf16 row-major (LN output)
// BT: [N][2048]     bf16 row-major (transposed weights)
// LDS: As[128][64] + Bs[128][64] bf16 (16KB each). Row = 128B = 8 granules.
// Swizzle: phys granule = logical ^ (row&7). Stage source pre-XORed, dest
// linear (global_load_lds: wave base + lane*16), reads apply same XOR.
// Grid: 1D XCD-chunk swizzled, y(N)-fastest decode (A-panel L2 locality).
template <int EPI>
__global__ __launch_bounds__(NTH, 3) void gemm97(const unsigned short* __restrict__ A,
                                                 const unsigned short* __restrict__ BT,
                                                 const float* __restrict__ bias,
                                                 const float* __restrict__ h,
                                                 unsigned short* __restrict__ hr,
                                                 float* __restrict__ zbuf,
                                                 float* __restrict__ outp,
                                                 int NYB) {
    __shared__ unsigned short As[8192];   // [128][64] bf16, 16KB
    __shared__ unsigned short Bs[8192];
    const int tid  = threadIdx.x;
    const int lane = tid & 63;
    const int w    = tid >> 6;        // 0..3
    const int wm   = w >> 1;          // 0..1 (M-warp)
    const int wn   = w & 1;           // 0..1 (N-warp)
    const int q    = lane >> 4;       // 0..3 (K-chunk)
    const int r16  = lane & 15;

    // XCD-chunk swizzle (bijective: nwg % 8 == 0), y-fastest decode
    const int nwg = gridDim.x;
    const int cid = (blockIdx.x & 7) * (nwg >> 3) + (blockIdx.x >> 3);
    const size_t m0 = (size_t)(cid / NYB) * 128;
    const int    n0 = (cid % NYB) * 128;

    const unsigned short* Ag = A  + m0 * TWOD;
    const unsigned short* Bg = BT + (size_t)n0 * TWOD;

    // staging: tile = 128 rows x 8 granules = 1024 granules; thread t covers
    // granules t, t+256, t+512, t+768 (rows r0, r0+32, r0+64, r0+96).
    // source col-granule pre-XORed with row&7 (same parity for all 4 chunks).
    const int r0 = tid >> 3;                         // 0..31
    const int sg = (tid & 7) ^ (r0 & 7);
    const unsigned short* aS0 = Ag + (size_t)r0 * TWOD + sg * 8;
    const unsigned short* aS1 = Ag + (size_t)(r0 + 32) * TWOD + sg * 8;
    const unsigned short* aS2 = Ag + (size_t)(r0 + 64) * TWOD + sg * 8;
    const unsigned short* aS3 = Ag + (size_t)(r0 + 96) * TWOD + sg * 8;
    const unsigned short* bS0 = Bg + (size_t)r0 * TWOD + sg * 8;
    const unsigned short* bS1 = Bg + (size_t)(r0 + 32) * TWOD + sg * 8;
    const unsigned short* bS2 = Bg + (size_t)(r0 + 64) * TWOD + sg * 8;
    const unsigned short* bS3 = Bg + (size_t)(r0 + 96) * TWOD + sg * 8;
    const unsigned dst = (unsigned)w * 1024u;        // + lane*16 by HW

    // frag reads: row = (wm|wn)*64 + i*16 + r16; sub-k s, chunk q ->
    // phys granule = (s*4+q) ^ (r16&7); byte = row*128 + pg*16.
    const unsigned arow = (unsigned)((wm * 64 + r16) * 128);   // + i*2048
    const unsigned brow = (unsigned)((wn * 64 + r16) * 128);   // + n*2048
    const unsigned pg0  = (unsigned)(((0 * 4 + q) ^ (r16 & 7)) * 16);
    const unsigned pg1  = (unsigned)(((1 * 4 + q) ^ (r16 & 7)) * 16);

    f32x4 acc[4][4] = {};
    const int NT = TWOD / GBK;   // 32

    for (int T = 0; T < NT; ++T) {
        const int k_ = T * GBK;
        gload16(aS0 + k_, (char*)As + dst);
        gload16(aS1 + k_, (char*)As + dst + 4096u);
        gload16(aS2 + k_, (char*)As + dst + 8192u);
        gload16(aS3 + k_, (char*)As + dst + 12288u);
        gload16(bS0 + k_, (char*)Bs + dst);
        gload16(bS1 + k_, (char*)Bs + dst + 4096u);
        gload16(bS2 + k_, (char*)Bs + dst + 8192u);
        gload16(bS3 + k_, (char*)Bs + dst + 12288u);
        __syncthreads();                 // full drain (m97 semantics)
        {
            bf16x8 af[4], bfr[4];
#pragma unroll
            for (int n = 0; n < 4; ++n)
                bfr[n] = *(const bf16x8*)((const char*)Bs + brow + (unsigned)n * 2048u + pg0);
#pragma unroll
            for (int i = 0; i < 4; ++i)
                af[i] = *(const bf16x8*)((const char*)As + arow + (unsigned)i * 2048u + pg0);
#pragma unroll
            for (int i = 0; i < 4; ++i)
#pragma unroll
                for (int n = 0; n < 4; ++n)
                    acc[i][n] = __builtin_amdgcn_mfma_f32_16x16x32_bf16(af[i], bfr[n], acc[i][n], 0, 0, 0);
        }
        {
            bf16x8 af[4], bfr[4];
#pragma unroll
            for (int n = 0; n < 4; ++n)
                bfr[n] = *(const bf16x8*)((const char*)Bs + brow + (unsigned)n * 2048u + pg1);
#pragma unroll
            for (int i = 0; i < 4; ++i)
                af[i] = *(const bf16x8*)((const char*)As + arow + (unsigned)i * 2048u + pg1);
#pragma unroll
            for (int i = 0; i < 4; ++i)
#pragma unroll
                for (int n = 0; n < 4; ++n)
                    acc[i][n] = __builtin_amdgcn_mfma_f32_16x16x32_bf16(af[i], bfr[n], acc[i][n], 0, 0, 0);
        }
        __syncthreads();
    }

    // epilogue: D col = lane&15, row = (lane>>4)*4 + reg  [verified m89/m91]
#pragma unroll
    for (int n = 0; n < 4; ++n) {
        const int col = n0 + wn * 64 + n * 16 + r16;
        const float bc = bias[col];
#pragma unroll
        for (int m = 0; m < 4; ++m) {
#pragma unroll
            for (int rg = 0; rg < 4; ++rg) {
                const size_t row = m0 + wm * 64 + m * 16 + q * 4 + rg;
                const float v = acc[m][n][rg] + bc;
                if (EPI == 0) {
                    if (n0 < DDIM) {
                        const float rr = 1.0f / (1.0f + __expf(-v));
                        const size_t idx = row * DDIM + col;
                        hr[idx] = f2bf(h[idx] * rr);
                    } else {
                        const float zz = 1.0f / (1.0f + __expf(-v));
                        zbuf[row * DDIM + (col - DDIM)] = zz;
                    }
                } else {
                    const float u = tanhf(v);
                    const size_t idx = row * DDIM + col;
                    const float zz = zbuf[idx];
                    const float hv = h[idx];
                    outp[idx] = hv * zz + (1.0f - zz) * u;
                }
            }
        }
    }
}

// --------------------------------------------------------------------------
extern "C" void kernel_launch(void* const* d_in, const int* in_sizes, int n_in,
                              void* d_out, int out_size, void* d_ws, size_t ws_size,
                              hipStream_t stream) {
    const float* x  = (const float*)d_in[0];
    const float* h  = (const float*)d_in[1];
    const float* Wg = (const float*)d_in[2];
    const float* bg = (const float*)d_in[3];
    const float* Wu = (const float*)d_in[4];
    const float* bu = (const float*)d_in[5];
    const float* g1 = (const float*)d_in[6];
    const float* b1 = (const float*)d_in[7];
    const float* g2 = (const float*)d_in[8];
    const float* b2 = (const float*)d_in[9];
    const float* dm = (const float*)d_in[10];
    float* out = (float*)d_out;

    char* ws = (char*)d_ws;
    unsigned short* WgT = (unsigned short*)(ws);                    // 8 MB
    unsigned short* WuT = (unsigned short*)(ws + 8388608);          // 4 MB
    unsigned short* ln  = (unsigned short*)(ws + 12582912);         // 64 MB
    unsigned short* hr  = (unsigned short*)(ws + 79691776);         // 32 MB

    wtrans<<<dim3(64, 64), 256, 0, stream>>>(Wg, WgT, TWOD, TWOD);
    wtrans<<<dim3(64, 32), 256, 0, stream>>>(Wu, WuT, TWOD, DDIM);
    ln_kernel<false><<<BATCH, 256, 0, stream>>>(x, (const void*)h, g1, b1, dm, ln);
    // GEMM1: 128 M-blocks x 16 N-blocks = 2048 (div 8 ok)
    gemm97<0><<<2048, NTH, 0, stream>>>(ln, WgT, bg, h, hr, out, nullptr, 16);
    ln_kernel<true><<<BATCH, 256, 0, stream>>>(x, (const void*)hr, g2, b2, dm, ln);
    // GEMM2: 128 x 8 = 1024 (div 8 ok)
    gemm97<1><<<1024, NTH, 0, stream>>>(ln, WuT, bu, h, nullptr, out, out, 8);
}